// Round 11
// baseline (192.656 us; speedup 1.0000x reference)
//
#include <hip/hip_runtime.h>

// LightGCN, z-form: z = dis(.)x  =>  z_k[c] = invdeg_c * sum_{r->c} z_{k-1}[r]
//   out = 0.25*(emb + sdeg (.) (z1+z2+z3)),  sdeg = sqrt(deg), dis = 1/sdeg.
// Build: radix partition by target bucket (128 nodes), per-bucket counting
// sort -> per-node CSR PADDED to multiple of 8 (dummy src = n -> zero row),
// then per-node ASCENDING source sort (waves sweep z in phase -> L2 window
// reuse instead of random-evict; the fetch-floor lever, R10 theory).
// Prop: 8-lane group per node (8 nodes/wave), lane = uint4 = 8 bf16 dims,
// guard-free 8-edge (2-quad) unroll. fp32 accumulate, no cross-lane reduce.
// NOTE: cooperative fusion tried R8/R9 — correct but 6x slower; abandoned.

#define BKT_SHIFT 7
#define BKT_NODES 128
#define BKT_CAP   2816      // mean 1600 edges + pad8 + slack
#define EPB       2048      // edges per k_bin block

__device__ __forceinline__ float lo2f(unsigned u) { return __uint_as_float(u << 16); }
__device__ __forceinline__ float hi2f(unsigned u) { return __uint_as_float(u & 0xFFFF0000u); }
__device__ __forceinline__ unsigned cvt_pk_bf16(float lo, float hi) {
  unsigned r;
  asm("v_cvt_pk_bf16_f32 %0, %1, %2" : "=v"(r) : "v"(lo), "v"(hi));
  return r;
}

__device__ __forceinline__ int wave_scan_incl(int v, int lane) {
#pragma unroll
  for (int off = 1; off < 64; off <<= 1) {
    int t = __shfl_up(v, off, 64);
    if (lane >= off) v += t;
  }
  return v;
}

// init bucket cursors + zero the dummy row n of z0/z1/z2
__global__ void k_init(int* __restrict__ bcursor, int nbkt,
                       unsigned* __restrict__ z0, unsigned* __restrict__ z1,
                       unsigned* __restrict__ z2, int n) {
  int i = blockIdx.x * blockDim.x + threadIdx.x;
  if (i < nbkt) bcursor[i] = i * BKT_CAP;
  if (blockIdx.x == 0 && threadIdx.x < 32) {     // row = 64 bf16 = 32 uints
    size_t o = (size_t)n * 32 + threadIdx.x;
    z0[o] = 0u; z1[o] = 0u; z2[o] = 0u;
  }
}

// radix partition by target bucket; LDS-aggregated so global atomics are
// one per (block, bin) and record writes are grouped per bin.
__global__ __launch_bounds__(256)
void k_bin(const int* __restrict__ row, const int* __restrict__ col,
           int* __restrict__ bcursor, int* __restrict__ tmp, int E, int nbkt) {
  __shared__ int h[1024];                 // nbkt <= 1024
  int e0 = blockIdx.x * EPB;
  int e1 = min(e0 + EPB, E);
  for (int i = threadIdx.x; i < nbkt; i += 256) h[i] = 0;
  __syncthreads();
  for (int e = e0 + threadIdx.x; e < e1; e += 256)
    atomicAdd(&h[col[e] >> BKT_SHIFT], 1);
  __syncthreads();
  for (int i = threadIdx.x; i < nbkt; i += 256) {
    int c = h[i];
    h[i] = c ? atomicAdd(&bcursor[i], c) : 0;   // reserve range, h -> base
  }
  __syncthreads();
  for (int e = e0 + threadIdx.x; e < e1; e += 256) {
    int c = col[e], r = row[e];
    int p = atomicAdd(&h[c >> BKT_SHIFT], 1);
    tmp[p] = r | ((c & (BKT_NODES - 1)) << 20);
  }
}

// per-bucket counting sort -> pad8 per-node CSR (sources sorted ascending);
// deg stats; z0 = bf16(dis*emb)
__global__ __launch_bounds__(256)
void k_sort(const int* __restrict__ bcursor, const int* __restrict__ tmp,
            int* __restrict__ srcs, int* __restrict__ obeg, int* __restrict__ oend,
            float* __restrict__ invdeg, float* __restrict__ sdeg,
            const float* __restrict__ emb, unsigned short* __restrict__ z0, int n) {
  __shared__ int hist[BKT_NODES];
  __shared__ int excl[BKT_NODES];
  __shared__ int cur[BKT_NODES];
  __shared__ float sdis[BKT_NODES];
  int b = blockIdx.x;
  int base = b * BKT_CAP;
  int cnt = bcursor[b] - base;
  if (threadIdx.x < BKT_NODES) hist[threadIdx.x] = 0;
  __syncthreads();
  for (int q = threadIdx.x; q < cnt; q += 256)
    atomicAdd(&hist[(unsigned)tmp[base + q] >> 20], 1);
  __syncthreads();
  if (threadIdx.x < 64) {     // scan PAD8 lengths; lane l owns bins 2l, 2l+1
    int l = threadIdx.x;
    int h0 = hist[2 * l], h1 = hist[2 * l + 1];
    int p0 = (h0 + 7) & ~7, p1 = (h1 + 7) & ~7;
    int v = p0 + p1;
    int incl = wave_scan_incl(v, l);
    int ex = incl - v;
    excl[2 * l] = ex;      excl[2 * l + 1] = ex + p0;
    cur[2 * l] = ex;       cur[2 * l + 1] = ex + p0;
  }
  __syncthreads();
  int node0 = b << BKT_SHIFT;
  if (threadIdx.x < BKT_NODES) {
    int node = node0 + threadIdx.x;
    if (node < n) {
      int d = hist[threadIdx.x];
      int dpad = (d + 7) & ~7;
      int bg = base + excl[threadIdx.x];
      obeg[node] = bg;
      oend[node] = bg + dpad;                 // padded end for the walk
      float fd = (float)d;
      invdeg[node] = d ? 1.0f / fd : 0.0f;
      sdeg[node] = sqrtf(fd);
      sdis[threadIdx.x] = d ? rsqrtf(fd) : 0.0f;
      for (int p = d; p < dpad; ++p) srcs[bg + p] = n;   // dummy -> zero row
    } else {
      sdis[threadIdx.x] = 0.0f;
    }
  }
  __syncthreads();
  for (int q = threadIdx.x; q < cnt; q += 256) {
    int rec = tmp[base + q];
    int lc = (unsigned)rec >> 20;
    int p = atomicAdd(&cur[lc], 1);
    srcs[base + p] = rec & 0xFFFFF;
  }
  __syncthreads();    // scatter complete before per-node sort reads srcs

  // z0 = bf16(dis * emb), coalesced across all 256 threads
  int nloc = min(BKT_NODES, n - node0);
  for (int t = threadIdx.x; t < nloc * 8; t += 256) {
    int rr = t >> 3, q = t & 7;
    float ds = sdis[rr];
    float4 v0 = reinterpret_cast<const float4*>(emb)[(size_t)(node0 + rr) * 16 + 2 * q];
    float4 v1 = reinterpret_cast<const float4*>(emb)[(size_t)(node0 + rr) * 16 + 2 * q + 1];
    uint4 o;
    o.x = cvt_pk_bf16(v0.x * ds, v0.y * ds);
    o.y = cvt_pk_bf16(v0.z * ds, v0.w * ds);
    o.z = cvt_pk_bf16(v1.x * ds, v1.y * ds);
    o.w = cvt_pk_bf16(v1.z * ds, v1.w * ds);
    reinterpret_cast<uint4*>(z0)[(size_t)(node0 + rr) * 8 + q] = o;
  }

  // per-node ascending insertion sort of the compact segment (L1-hot, ~12.5
  // entries mean). Sorted walks make concurrent waves sweep z in phase ->
  // L2 window reuse in k_prop. Dummies (==n) already sit at the end.
  if (threadIdx.x < BKT_NODES) {
    int i = threadIdx.x;
    int node = node0 + i;
    if (node < n) {
      int bg = base + excl[i];
      int d = hist[i];
      for (int a = 1; a < d; ++a) {
        int key = srcs[bg + a];
        int j = a - 1;
        while (j >= 0 && srcs[bg + j] > key) {
          srcs[bg + j + 1] = srcs[bg + j];
          --j;
        }
        srcs[bg + j + 1] = key;
      }
    }
  }
}

// 8-lane group per node, 8 nodes per wave; lane l covers dims 8l..8l+7 (uint4).
// Guard-free 2-quad (8-edge) unroll over pad8 CSR; 8 row gathers in flight.
template <bool FINAL>
__global__ __launch_bounds__(256)
void k_prop(const int* __restrict__ obeg, const int* __restrict__ oend,
            const int* __restrict__ srcs, const unsigned short* __restrict__ z,
            unsigned short* __restrict__ zout, const float* __restrict__ invdeg,
            const float* __restrict__ emb, const unsigned short* __restrict__ z1,
            const unsigned short* __restrict__ z2, const float* __restrict__ sdeg,
            float* __restrict__ out, int n) {
  int lane = threadIdx.x & 63;
  int wid = (blockIdx.x * blockDim.x + threadIdx.x) >> 6;   // global wave id
  int g = lane >> 3, l = lane & 7;
  int node = wid * 8 + g;
  if (node >= n) return;
  const uint4* zv = reinterpret_cast<const uint4*>(z);      // row = 8 x uint4
  const int4* sv = reinterpret_cast<const int4*>(srcs);

  int kq = obeg[node] >> 2;       // even by construction (pad8)
  int endq = oend[node] >> 2;     // endq - kq is even

  float s0 = 0.f, s1 = 0.f, s2 = 0.f, s3 = 0.f;
  float s4 = 0.f, s5 = 0.f, s6 = 0.f, s7 = 0.f;

  int4 sqA = make_int4(0, 0, 0, 0), sqB = sqA;
  if (kq < endq) { sqA = sv[kq]; sqB = sv[kq + 1]; }
  while (kq < endq) {
    uint4 a0 = zv[(size_t)sqA.x * 8 + l];
    uint4 a1 = zv[(size_t)sqA.y * 8 + l];
    uint4 a2 = zv[(size_t)sqA.z * 8 + l];
    uint4 a3 = zv[(size_t)sqA.w * 8 + l];
    uint4 b0 = zv[(size_t)sqB.x * 8 + l];
    uint4 b1 = zv[(size_t)sqB.y * 8 + l];
    uint4 b2 = zv[(size_t)sqB.z * 8 + l];
    uint4 b3 = zv[(size_t)sqB.w * 8 + l];
    kq += 2;
    int nk = (kq < endq) ? kq : (kq - 2);   // harmless re-read at the tail
    sqA = sv[nk];
    sqB = sv[nk + 1];
    s0 += lo2f(a0.x); s1 += hi2f(a0.x); s2 += lo2f(a0.y); s3 += hi2f(a0.y);
    s4 += lo2f(a0.z); s5 += hi2f(a0.z); s6 += lo2f(a0.w); s7 += hi2f(a0.w);
    s0 += lo2f(a1.x); s1 += hi2f(a1.x); s2 += lo2f(a1.y); s3 += hi2f(a1.y);
    s4 += lo2f(a1.z); s5 += hi2f(a1.z); s6 += lo2f(a1.w); s7 += hi2f(a1.w);
    s0 += lo2f(a2.x); s1 += hi2f(a2.x); s2 += lo2f(a2.y); s3 += hi2f(a2.y);
    s4 += lo2f(a2.z); s5 += hi2f(a2.z); s6 += lo2f(a2.w); s7 += hi2f(a2.w);
    s0 += lo2f(a3.x); s1 += hi2f(a3.x); s2 += lo2f(a3.y); s3 += hi2f(a3.y);
    s4 += lo2f(a3.z); s5 += hi2f(a3.z); s6 += lo2f(a3.w); s7 += hi2f(a3.w);
    s0 += lo2f(b0.x); s1 += hi2f(b0.x); s2 += lo2f(b0.y); s3 += hi2f(b0.y);
    s4 += lo2f(b0.z); s5 += hi2f(b0.z); s6 += lo2f(b0.w); s7 += hi2f(b0.w);
    s0 += lo2f(b1.x); s1 += hi2f(b1.x); s2 += lo2f(b1.y); s3 += hi2f(b1.y);
    s4 += lo2f(b1.z); s5 += hi2f(b1.z); s6 += lo2f(b1.w); s7 += hi2f(b1.w);
    s0 += lo2f(b2.x); s1 += hi2f(b2.x); s2 += lo2f(b2.y); s3 += hi2f(b2.y);
    s4 += lo2f(b2.z); s5 += hi2f(b2.z); s6 += lo2f(b2.w); s7 += hi2f(b2.w);
    s0 += lo2f(b3.x); s1 += hi2f(b3.x); s2 += lo2f(b3.y); s3 += hi2f(b3.y);
    s4 += lo2f(b3.z); s5 += hi2f(b3.z); s6 += lo2f(b3.w); s7 += hi2f(b3.w);
  }

  float idg = invdeg[node];
  size_t gi = (size_t)node * 8 + l;
  if (!FINAL) {
    uint4 o;
    o.x = cvt_pk_bf16(s0 * idg, s1 * idg);
    o.y = cvt_pk_bf16(s2 * idg, s3 * idg);
    o.z = cvt_pk_bf16(s4 * idg, s5 * idg);
    o.w = cvt_pk_bf16(s6 * idg, s7 * idg);
    reinterpret_cast<uint4*>(zout)[gi] = o;
  } else {
    float sd = sdeg[node];
    float c = sd * idg;
    uint4 a1 = reinterpret_cast<const uint4*>(z1)[gi];
    uint4 a2 = reinterpret_cast<const uint4*>(z2)[gi];
    float4 e0 = reinterpret_cast<const float4*>(emb)[(size_t)node * 16 + 2 * l];
    float4 e1 = reinterpret_cast<const float4*>(emb)[(size_t)node * 16 + 2 * l + 1];
    float4 o0, o1;
    o0.x = 0.25f * (e0.x + sd * (lo2f(a1.x) + lo2f(a2.x)) + c * s0);
    o0.y = 0.25f * (e0.y + sd * (hi2f(a1.x) + hi2f(a2.x)) + c * s1);
    o0.z = 0.25f * (e0.z + sd * (lo2f(a1.y) + lo2f(a2.y)) + c * s2);
    o0.w = 0.25f * (e0.w + sd * (hi2f(a1.y) + hi2f(a2.y)) + c * s3);
    o1.x = 0.25f * (e1.x + sd * (lo2f(a1.z) + lo2f(a2.z)) + c * s4);
    o1.y = 0.25f * (e1.y + sd * (hi2f(a1.z) + hi2f(a2.z)) + c * s5);
    o1.z = 0.25f * (e1.z + sd * (lo2f(a1.w) + lo2f(a2.w)) + c * s6);
    o1.w = 0.25f * (e1.w + sd * (hi2f(a1.w) + hi2f(a2.w)) + c * s7);
    reinterpret_cast<float4*>(out)[(size_t)node * 16 + 2 * l] = o0;
    reinterpret_cast<float4*>(out)[(size_t)node * 16 + 2 * l + 1] = o1;
  }
}

extern "C" void kernel_launch(void* const* d_in, const int* in_sizes, int n_in,
                              void* d_out, int out_size, void* d_ws, size_t ws_size,
                              hipStream_t stream) {
  const int* edge = (const int*)d_in[0];
  const float* emb = (const float*)d_in[1];
  float* out = (float*)d_out;

  const int E = in_sizes[0] / 2;
  const int n = in_sizes[1] / 64;
  const int* row = edge;        // sources j
  const int* col = edge + E;    // targets i
  const int NBKT = (n + BKT_NODES - 1) / BKT_NODES;   // 782

  char* ws = (char*)d_ws;
  size_t off = 0;
  auto alloc = [&](size_t bytes) -> void* {
    void* p = ws + off;
    off += (bytes + 255) & ~(size_t)255;
    return p;
  };
  int*   bcursor = (int*)  alloc((size_t)NBKT * 4);
  int*   tmp     = (int*)  alloc((size_t)NBKT * BKT_CAP * 4);   // ~8.8 MB
  int*   srcs    = (int*)  alloc((size_t)NBKT * BKT_CAP * 4);   // ~8.8 MB
  int*   obeg    = (int*)  alloc((size_t)n * 4);
  int*   oend    = (int*)  alloc((size_t)n * 4);
  float* invdeg  = (float*)alloc((size_t)n * 4);
  float* sdeg    = (float*)alloc((size_t)n * 4);
  unsigned short* z0 = (unsigned short*)alloc((size_t)(n + 1) * 64 * 2);
  unsigned short* z1 = (unsigned short*)alloc((size_t)(n + 1) * 64 * 2);
  unsigned short* z2 = (unsigned short*)alloc((size_t)(n + 1) * 64 * 2);
  (void)ws_size; (void)n_in; (void)out_size;

  const int NBB = (E + EPB - 1) / EPB;
  k_init<<<(NBKT + 255) / 256, 256, 0, stream>>>(bcursor, NBKT,
      (unsigned*)z0, (unsigned*)z1, (unsigned*)z2, n);
  k_bin<<<NBB, 256, 0, stream>>>(row, col, bcursor, tmp, E, NBKT);
  k_sort<<<NBKT, 256, 0, stream>>>(bcursor, tmp, srcs, obeg, oend,
                                   invdeg, sdeg, emb, z0, n);

  // 8 nodes per wave, 4 waves per block = 32 nodes/block
  const int pg = (n + 31) / 32;
  k_prop<false><<<pg, 256, 0, stream>>>(obeg, oend, srcs, z0, z1, invdeg,
                                        nullptr, nullptr, nullptr, nullptr, nullptr, n);
  k_prop<false><<<pg, 256, 0, stream>>>(obeg, oend, srcs, z1, z2, invdeg,
                                        nullptr, nullptr, nullptr, nullptr, nullptr, n);
  k_prop<true ><<<pg, 256, 0, stream>>>(obeg, oend, srcs, z2, nullptr, invdeg,
                                        emb, z1, z2, sdeg, out, n);
}

// Round 12
// 129.981 us; speedup vs baseline: 1.4822x; 1.4822x over previous
//
#include <hip/hip_runtime.h>

// LightGCN, z-form: z = dis(.)x  =>  z_k[c] = invdeg_c * sum_{r->c} z_{k-1}[r]
//   out = 0.25*(emb + sdeg (.) (z1+z2+z3)),  sdeg = sqrt(deg), dis = 1/sdeg.
// Build: radix partition by target bucket (128 nodes), per-bucket counting
// sort -> per-node CSR PADDED to multiple of 8 (dummy src = n -> zero row).
// Prop: 8-lane group per node (8 nodes/wave), lane = uint4 = 8 bf16 dims,
// guard-free 8-edge (2-quad) unroll; bf16 accumulate via v_dot2_f32_bf16
// (1 inst per dim: fused unpack+add). fp32 accumulators, no cross-lane reduce.
// NOTES: coop fusion (R8/R9) 6x slower — abandoned. Per-node src sort (R11)
// cost 75us, saved <4/prop — FETCH==8 XCD x z_size is the compulsory floor.

#define BKT_SHIFT 7
#define BKT_NODES 128
#define BKT_CAP   2816      // mean 1600 edges + pad8 + slack
#define EPB       2048      // edges per k_bin block

__device__ __forceinline__ float lo2f(unsigned u) { return __uint_as_float(u << 16); }
__device__ __forceinline__ float hi2f(unsigned u) { return __uint_as_float(u & 0xFFFF0000u); }
__device__ __forceinline__ unsigned cvt_pk_bf16(float lo, float hi) {
  unsigned r;
  asm("v_cvt_pk_bf16_f32 %0, %1, %2" : "=v"(r) : "v"(lo), "v"(hi));
  return r;
}

// s_lo += bf16_lo(u); s_hi += bf16_hi(u)  — one v_dot2 each (B=(1,0)/(0,1))
#define ACC2(u, slo, shi)                                                     \
  asm("v_dot2_f32_bf16 %0, %1, %2, %0" : "+v"(slo) : "v"(u), "v"(c_lo));      \
  asm("v_dot2_f32_bf16 %0, %1, %2, %0" : "+v"(shi) : "v"(u), "v"(c_hi));

__device__ __forceinline__ int wave_scan_incl(int v, int lane) {
#pragma unroll
  for (int off = 1; off < 64; off <<= 1) {
    int t = __shfl_up(v, off, 64);
    if (lane >= off) v += t;
  }
  return v;
}

// init bucket cursors + zero the dummy row n of z0/z1/z2
__global__ void k_init(int* __restrict__ bcursor, int nbkt,
                       unsigned* __restrict__ z0, unsigned* __restrict__ z1,
                       unsigned* __restrict__ z2, int n) {
  int i = blockIdx.x * blockDim.x + threadIdx.x;
  if (i < nbkt) bcursor[i] = i * BKT_CAP;
  if (blockIdx.x == 0 && threadIdx.x < 32) {     // row = 64 bf16 = 32 uints
    size_t o = (size_t)n * 32 + threadIdx.x;
    z0[o] = 0u; z1[o] = 0u; z2[o] = 0u;
  }
}

// radix partition by target bucket; LDS-aggregated so global atomics are
// one per (block, bin) and record writes are grouped per bin.
__global__ __launch_bounds__(256)
void k_bin(const int* __restrict__ row, const int* __restrict__ col,
           int* __restrict__ bcursor, int* __restrict__ tmp, int E, int nbkt) {
  __shared__ int h[1024];                 // nbkt <= 1024
  int e0 = blockIdx.x * EPB;
  int e1 = min(e0 + EPB, E);
  for (int i = threadIdx.x; i < nbkt; i += 256) h[i] = 0;
  __syncthreads();
  for (int e = e0 + threadIdx.x; e < e1; e += 256)
    atomicAdd(&h[col[e] >> BKT_SHIFT], 1);
  __syncthreads();
  for (int i = threadIdx.x; i < nbkt; i += 256) {
    int c = h[i];
    h[i] = c ? atomicAdd(&bcursor[i], c) : 0;   // reserve range, h -> base
  }
  __syncthreads();
  for (int e = e0 + threadIdx.x; e < e1; e += 256) {
    int c = col[e], r = row[e];
    int p = atomicAdd(&h[c >> BKT_SHIFT], 1);
    tmp[p] = r | ((c & (BKT_NODES - 1)) << 20);
  }
}

// per-bucket counting sort -> pad8 per-node CSR; deg stats; z0 = bf16(dis*emb)
__global__ __launch_bounds__(256)
void k_sort(const int* __restrict__ bcursor, const int* __restrict__ tmp,
            int* __restrict__ srcs, int* __restrict__ obeg, int* __restrict__ oend,
            float* __restrict__ invdeg, float* __restrict__ sdeg,
            const float* __restrict__ emb, unsigned short* __restrict__ z0, int n) {
  __shared__ int hist[BKT_NODES];
  __shared__ int excl[BKT_NODES];
  __shared__ int cur[BKT_NODES];
  __shared__ float sdis[BKT_NODES];
  int b = blockIdx.x;
  int base = b * BKT_CAP;
  int cnt = bcursor[b] - base;
  if (threadIdx.x < BKT_NODES) hist[threadIdx.x] = 0;
  __syncthreads();
  for (int q = threadIdx.x; q < cnt; q += 256)
    atomicAdd(&hist[(unsigned)tmp[base + q] >> 20], 1);
  __syncthreads();
  if (threadIdx.x < 64) {     // scan PAD8 lengths; lane l owns bins 2l, 2l+1
    int l = threadIdx.x;
    int h0 = hist[2 * l], h1 = hist[2 * l + 1];
    int p0 = (h0 + 7) & ~7, p1 = (h1 + 7) & ~7;
    int v = p0 + p1;
    int incl = wave_scan_incl(v, l);
    int ex = incl - v;
    excl[2 * l] = ex;      excl[2 * l + 1] = ex + p0;
    cur[2 * l] = ex;       cur[2 * l + 1] = ex + p0;
  }
  __syncthreads();
  int node0 = b << BKT_SHIFT;
  if (threadIdx.x < BKT_NODES) {
    int node = node0 + threadIdx.x;
    if (node < n) {
      int d = hist[threadIdx.x];
      int dpad = (d + 7) & ~7;
      int bg = base + excl[threadIdx.x];
      obeg[node] = bg;
      oend[node] = bg + dpad;                 // padded end for the walk
      float fd = (float)d;
      invdeg[node] = d ? 1.0f / fd : 0.0f;
      sdeg[node] = sqrtf(fd);
      sdis[threadIdx.x] = d ? rsqrtf(fd) : 0.0f;
      for (int p = d; p < dpad; ++p) srcs[bg + p] = n;   // dummy -> zero row
    } else {
      sdis[threadIdx.x] = 0.0f;
    }
  }
  __syncthreads();
  for (int q = threadIdx.x; q < cnt; q += 256) {
    int rec = tmp[base + q];
    int lc = (unsigned)rec >> 20;
    int p = atomicAdd(&cur[lc], 1);
    srcs[base + p] = rec & 0xFFFFF;
  }
  int nloc = min(BKT_NODES, n - node0);
  for (int t = threadIdx.x; t < nloc * 8; t += 256) {
    int rr = t >> 3, q = t & 7;
    float ds = sdis[rr];
    float4 v0 = reinterpret_cast<const float4*>(emb)[(size_t)(node0 + rr) * 16 + 2 * q];
    float4 v1 = reinterpret_cast<const float4*>(emb)[(size_t)(node0 + rr) * 16 + 2 * q + 1];
    uint4 o;
    o.x = cvt_pk_bf16(v0.x * ds, v0.y * ds);
    o.y = cvt_pk_bf16(v0.z * ds, v0.w * ds);
    o.z = cvt_pk_bf16(v1.x * ds, v1.y * ds);
    o.w = cvt_pk_bf16(v1.z * ds, v1.w * ds);
    reinterpret_cast<uint4*>(z0)[(size_t)(node0 + rr) * 8 + q] = o;
  }
}

// 8-lane group per node, 8 nodes per wave; lane l covers dims 8l..8l+7 (uint4).
// Guard-free 2-quad (8-edge) unroll over pad8 CSR; dot2-based accumulate.
template <bool FINAL>
__global__ __launch_bounds__(256)
void k_prop(const int* __restrict__ obeg, const int* __restrict__ oend,
            const int* __restrict__ srcs, const unsigned short* __restrict__ z,
            unsigned short* __restrict__ zout, const float* __restrict__ invdeg,
            const float* __restrict__ emb, const unsigned short* __restrict__ z1,
            const unsigned short* __restrict__ z2, const float* __restrict__ sdeg,
            float* __restrict__ out, int n) {
  int lane = threadIdx.x & 63;
  int wid = (blockIdx.x * blockDim.x + threadIdx.x) >> 6;   // global wave id
  int g = lane >> 3, l = lane & 7;
  int node = wid * 8 + g;
  if (node >= n) return;
  const uint4* zv = reinterpret_cast<const uint4*>(z);      // row = 8 x uint4
  const int4* sv = reinterpret_cast<const int4*>(srcs);

  const unsigned c_lo = 0x00003F80u;   // B=(1.0bf16, 0)  -> adds lo half
  const unsigned c_hi = 0x3F800000u;   // B=(0, 1.0bf16)  -> adds hi half

  int kq = obeg[node] >> 2;       // even by construction (pad8)
  int endq = oend[node] >> 2;     // endq - kq is even

  float s0 = 0.f, s1 = 0.f, s2 = 0.f, s3 = 0.f;
  float s4 = 0.f, s5 = 0.f, s6 = 0.f, s7 = 0.f;

  int4 sqA = make_int4(0, 0, 0, 0), sqB = sqA;
  if (kq < endq) { sqA = sv[kq]; sqB = sv[kq + 1]; }
  while (kq < endq) {
    uint4 a0 = zv[(size_t)sqA.x * 8 + l];
    uint4 a1 = zv[(size_t)sqA.y * 8 + l];
    uint4 a2 = zv[(size_t)sqA.z * 8 + l];
    uint4 a3 = zv[(size_t)sqA.w * 8 + l];
    uint4 b0 = zv[(size_t)sqB.x * 8 + l];
    uint4 b1 = zv[(size_t)sqB.y * 8 + l];
    uint4 b2 = zv[(size_t)sqB.z * 8 + l];
    uint4 b3 = zv[(size_t)sqB.w * 8 + l];
    kq += 2;
    int nk = (kq < endq) ? kq : (kq - 2);   // harmless re-read at the tail
    sqA = sv[nk];
    sqB = sv[nk + 1];
    ACC2(a0.x, s0, s1); ACC2(a0.y, s2, s3); ACC2(a0.z, s4, s5); ACC2(a0.w, s6, s7);
    ACC2(a1.x, s0, s1); ACC2(a1.y, s2, s3); ACC2(a1.z, s4, s5); ACC2(a1.w, s6, s7);
    ACC2(a2.x, s0, s1); ACC2(a2.y, s2, s3); ACC2(a2.z, s4, s5); ACC2(a2.w, s6, s7);
    ACC2(a3.x, s0, s1); ACC2(a3.y, s2, s3); ACC2(a3.z, s4, s5); ACC2(a3.w, s6, s7);
    ACC2(b0.x, s0, s1); ACC2(b0.y, s2, s3); ACC2(b0.z, s4, s5); ACC2(b0.w, s6, s7);
    ACC2(b1.x, s0, s1); ACC2(b1.y, s2, s3); ACC2(b1.z, s4, s5); ACC2(b1.w, s6, s7);
    ACC2(b2.x, s0, s1); ACC2(b2.y, s2, s3); ACC2(b2.z, s4, s5); ACC2(b2.w, s6, s7);
    ACC2(b3.x, s0, s1); ACC2(b3.y, s2, s3); ACC2(b3.z, s4, s5); ACC2(b3.w, s6, s7);
  }

  float idg = invdeg[node];
  size_t gi = (size_t)node * 8 + l;
  if (!FINAL) {
    uint4 o;
    o.x = cvt_pk_bf16(s0 * idg, s1 * idg);
    o.y = cvt_pk_bf16(s2 * idg, s3 * idg);
    o.z = cvt_pk_bf16(s4 * idg, s5 * idg);
    o.w = cvt_pk_bf16(s6 * idg, s7 * idg);
    reinterpret_cast<uint4*>(zout)[gi] = o;
  } else {
    float sd = sdeg[node];
    float c = sd * idg;
    uint4 a1 = reinterpret_cast<const uint4*>(z1)[gi];
    uint4 a2 = reinterpret_cast<const uint4*>(z2)[gi];
    float4 e0 = reinterpret_cast<const float4*>(emb)[(size_t)node * 16 + 2 * l];
    float4 e1 = reinterpret_cast<const float4*>(emb)[(size_t)node * 16 + 2 * l + 1];
    float4 o0, o1;
    o0.x = 0.25f * (e0.x + sd * (lo2f(a1.x) + lo2f(a2.x)) + c * s0);
    o0.y = 0.25f * (e0.y + sd * (hi2f(a1.x) + hi2f(a2.x)) + c * s1);
    o0.z = 0.25f * (e0.z + sd * (lo2f(a1.y) + lo2f(a2.y)) + c * s2);
    o0.w = 0.25f * (e0.w + sd * (hi2f(a1.y) + hi2f(a2.y)) + c * s3);
    o1.x = 0.25f * (e1.x + sd * (lo2f(a1.z) + lo2f(a2.z)) + c * s4);
    o1.y = 0.25f * (e1.y + sd * (hi2f(a1.z) + hi2f(a2.z)) + c * s5);
    o1.z = 0.25f * (e1.z + sd * (lo2f(a1.w) + lo2f(a2.w)) + c * s6);
    o1.w = 0.25f * (e1.w + sd * (hi2f(a1.w) + hi2f(a2.w)) + c * s7);
    reinterpret_cast<float4*>(out)[(size_t)node * 16 + 2 * l] = o0;
    reinterpret_cast<float4*>(out)[(size_t)node * 16 + 2 * l + 1] = o1;
  }
}

extern "C" void kernel_launch(void* const* d_in, const int* in_sizes, int n_in,
                              void* d_out, int out_size, void* d_ws, size_t ws_size,
                              hipStream_t stream) {
  const int* edge = (const int*)d_in[0];
  const float* emb = (const float*)d_in[1];
  float* out = (float*)d_out;

  const int E = in_sizes[0] / 2;
  const int n = in_sizes[1] / 64;
  const int* row = edge;        // sources j
  const int* col = edge + E;    // targets i
  const int NBKT = (n + BKT_NODES - 1) / BKT_NODES;   // 782

  char* ws = (char*)d_ws;
  size_t off = 0;
  auto alloc = [&](size_t bytes) -> void* {
    void* p = ws + off;
    off += (bytes + 255) & ~(size_t)255;
    return p;
  };
  int*   bcursor = (int*)  alloc((size_t)NBKT * 4);
  int*   tmp     = (int*)  alloc((size_t)NBKT * BKT_CAP * 4);   // ~8.8 MB
  int*   srcs    = (int*)  alloc((size_t)NBKT * BKT_CAP * 4);   // ~8.8 MB
  int*   obeg    = (int*)  alloc((size_t)n * 4);
  int*   oend    = (int*)  alloc((size_t)n * 4);
  float* invdeg  = (float*)alloc((size_t)n * 4);
  float* sdeg    = (float*)alloc((size_t)n * 4);
  unsigned short* z0 = (unsigned short*)alloc((size_t)(n + 1) * 64 * 2);
  unsigned short* z1 = (unsigned short*)alloc((size_t)(n + 1) * 64 * 2);
  unsigned short* z2 = (unsigned short*)alloc((size_t)(n + 1) * 64 * 2);
  (void)ws_size; (void)n_in; (void)out_size;

  const int NBB = (E + EPB - 1) / EPB;
  k_init<<<(NBKT + 255) / 256, 256, 0, stream>>>(bcursor, NBKT,
      (unsigned*)z0, (unsigned*)z1, (unsigned*)z2, n);
  k_bin<<<NBB, 256, 0, stream>>>(row, col, bcursor, tmp, E, NBKT);
  k_sort<<<NBKT, 256, 0, stream>>>(bcursor, tmp, srcs, obeg, oend,
                                   invdeg, sdeg, emb, z0, n);

  // 8 nodes per wave, 4 waves per block = 32 nodes/block
  const int pg = (n + 31) / 32;
  k_prop<false><<<pg, 256, 0, stream>>>(obeg, oend, srcs, z0, z1, invdeg,
                                        nullptr, nullptr, nullptr, nullptr, nullptr, n);
  k_prop<false><<<pg, 256, 0, stream>>>(obeg, oend, srcs, z1, z2, invdeg,
                                        nullptr, nullptr, nullptr, nullptr, nullptr, n);
  k_prop<true ><<<pg, 256, 0, stream>>>(obeg, oend, srcs, z2, nullptr, invdeg,
                                        emb, z1, z2, sdeg, out, n);
}

// Round 13
// 126.148 us; speedup vs baseline: 1.5272x; 1.0304x over previous
//
#include <hip/hip_runtime.h>

// LightGCN, z-form: z = dis(.)x  =>  z_k[c] = invdeg_c * sum_{r->c} z_{k-1}[r]
//   out = 0.25*(emb + sdeg (.) (z1+z2+z3)),  sdeg = sqrt(deg), dis = 1/sdeg.
// Build: radix partition by target bucket (128 nodes), per-bucket counting
// sort -> per-node CSR PADDED to multiple of 8 (dummy src = n -> zero row).
// Prop: 8-lane group per node (8 nodes/wave), lane = uint4 = 8 bf16 dims,
// guard-free 8-edge (2-quad) unroll; bf16 accumulate via v_dot2_f32_bf16.
// NOTES: coop fusion (R8/R9) 6x slower — abandoned. Per-node src sort (R11)
// regressed. Prop loop fabric-bound: FETCH == 8 XCD x z_size compulsory floor
// (MLP/instr-count changes R9/R10/R12 all null). EPB=2048 (R5) was a silent
// k_bin regression (40us: 478K hot atomics + 10B write bursts) -> back to 8192.

#define BKT_SHIFT 7
#define BKT_NODES 128
#define BKT_CAP   2816      // mean 1600 edges + pad8 + slack
#define EPB       8192      // edges per k_bin block (153 blocks)

__device__ __forceinline__ float lo2f(unsigned u) { return __uint_as_float(u << 16); }
__device__ __forceinline__ float hi2f(unsigned u) { return __uint_as_float(u & 0xFFFF0000u); }
__device__ __forceinline__ unsigned cvt_pk_bf16(float lo, float hi) {
  unsigned r;
  asm("v_cvt_pk_bf16_f32 %0, %1, %2" : "=v"(r) : "v"(lo), "v"(hi));
  return r;
}

// s_lo += bf16_lo(u); s_hi += bf16_hi(u)  — one v_dot2 each (B=(1,0)/(0,1))
#define ACC2(u, slo, shi)                                                     \
  asm("v_dot2_f32_bf16 %0, %1, %2, %0" : "+v"(slo) : "v"(u), "v"(c_lo));      \
  asm("v_dot2_f32_bf16 %0, %1, %2, %0" : "+v"(shi) : "v"(u), "v"(c_hi));

__device__ __forceinline__ int wave_scan_incl(int v, int lane) {
#pragma unroll
  for (int off = 1; off < 64; off <<= 1) {
    int t = __shfl_up(v, off, 64);
    if (lane >= off) v += t;
  }
  return v;
}

// init bucket cursors + zero the dummy row n of z0/z1/z2
__global__ void k_init(int* __restrict__ bcursor, int nbkt,
                       unsigned* __restrict__ z0, unsigned* __restrict__ z1,
                       unsigned* __restrict__ z2, int n) {
  int i = blockIdx.x * blockDim.x + threadIdx.x;
  if (i < nbkt) bcursor[i] = i * BKT_CAP;
  if (blockIdx.x == 0 && threadIdx.x < 32) {     // row = 64 bf16 = 32 uints
    size_t o = (size_t)n * 32 + threadIdx.x;
    z0[o] = 0u; z1[o] = 0u; z2[o] = 0u;
  }
}

// radix partition by target bucket; LDS-aggregated so global atomics are
// one per (block, bin) and record writes are grouped per bin.
__global__ __launch_bounds__(256)
void k_bin(const int* __restrict__ row, const int* __restrict__ col,
           int* __restrict__ bcursor, int* __restrict__ tmp, int E, int nbkt) {
  __shared__ int h[1024];                 // nbkt <= 1024
  int e0 = blockIdx.x * EPB;
  int e1 = min(e0 + EPB, E);
  for (int i = threadIdx.x; i < nbkt; i += 256) h[i] = 0;
  __syncthreads();
  for (int e = e0 + threadIdx.x; e < e1; e += 256)
    atomicAdd(&h[col[e] >> BKT_SHIFT], 1);
  __syncthreads();
  for (int i = threadIdx.x; i < nbkt; i += 256) {
    int c = h[i];
    h[i] = c ? atomicAdd(&bcursor[i], c) : 0;   // reserve range, h -> base
  }
  __syncthreads();
  for (int e = e0 + threadIdx.x; e < e1; e += 256) {
    int c = col[e], r = row[e];
    int p = atomicAdd(&h[c >> BKT_SHIFT], 1);
    tmp[p] = r | ((c & (BKT_NODES - 1)) << 20);
  }
}

// per-bucket counting sort -> pad8 per-node CSR; deg stats; z0 = bf16(dis*emb)
__global__ __launch_bounds__(256)
void k_sort(const int* __restrict__ bcursor, const int* __restrict__ tmp,
            int* __restrict__ srcs, int* __restrict__ obeg, int* __restrict__ oend,
            float* __restrict__ invdeg, float* __restrict__ sdeg,
            const float* __restrict__ emb, unsigned short* __restrict__ z0, int n) {
  __shared__ int hist[BKT_NODES];
  __shared__ int excl[BKT_NODES];
  __shared__ int cur[BKT_NODES];
  __shared__ float sdis[BKT_NODES];
  int b = blockIdx.x;
  int base = b * BKT_CAP;
  int cnt = bcursor[b] - base;
  if (threadIdx.x < BKT_NODES) hist[threadIdx.x] = 0;
  __syncthreads();
  for (int q = threadIdx.x; q < cnt; q += 256)
    atomicAdd(&hist[(unsigned)tmp[base + q] >> 20], 1);
  __syncthreads();
  if (threadIdx.x < 64) {     // scan PAD8 lengths; lane l owns bins 2l, 2l+1
    int l = threadIdx.x;
    int h0 = hist[2 * l], h1 = hist[2 * l + 1];
    int p0 = (h0 + 7) & ~7, p1 = (h1 + 7) & ~7;
    int v = p0 + p1;
    int incl = wave_scan_incl(v, l);
    int ex = incl - v;
    excl[2 * l] = ex;      excl[2 * l + 1] = ex + p0;
    cur[2 * l] = ex;       cur[2 * l + 1] = ex + p0;
  }
  __syncthreads();
  int node0 = b << BKT_SHIFT;
  if (threadIdx.x < BKT_NODES) {
    int node = node0 + threadIdx.x;
    if (node < n) {
      int d = hist[threadIdx.x];
      int dpad = (d + 7) & ~7;
      int bg = base + excl[threadIdx.x];
      obeg[node] = bg;
      oend[node] = bg + dpad;                 // padded end for the walk
      float fd = (float)d;
      invdeg[node] = d ? 1.0f / fd : 0.0f;
      sdeg[node] = sqrtf(fd);
      sdis[threadIdx.x] = d ? rsqrtf(fd) : 0.0f;
      for (int p = d; p < dpad; ++p) srcs[bg + p] = n;   // dummy -> zero row
    } else {
      sdis[threadIdx.x] = 0.0f;
    }
  }
  __syncthreads();
  for (int q = threadIdx.x; q < cnt; q += 256) {
    int rec = tmp[base + q];
    int lc = (unsigned)rec >> 20;
    int p = atomicAdd(&cur[lc], 1);
    srcs[base + p] = rec & 0xFFFFF;
  }
  int nloc = min(BKT_NODES, n - node0);
  for (int t = threadIdx.x; t < nloc * 8; t += 256) {
    int rr = t >> 3, q = t & 7;
    float ds = sdis[rr];
    float4 v0 = reinterpret_cast<const float4*>(emb)[(size_t)(node0 + rr) * 16 + 2 * q];
    float4 v1 = reinterpret_cast<const float4*>(emb)[(size_t)(node0 + rr) * 16 + 2 * q + 1];
    uint4 o;
    o.x = cvt_pk_bf16(v0.x * ds, v0.y * ds);
    o.y = cvt_pk_bf16(v0.z * ds, v0.w * ds);
    o.z = cvt_pk_bf16(v1.x * ds, v1.y * ds);
    o.w = cvt_pk_bf16(v1.z * ds, v1.w * ds);
    reinterpret_cast<uint4*>(z0)[(size_t)(node0 + rr) * 8 + q] = o;
  }
}

// 8-lane group per node, 8 nodes per wave; lane l covers dims 8l..8l+7 (uint4).
// Guard-free 2-quad (8-edge) unroll over pad8 CSR; dot2-based accumulate.
template <bool FINAL>
__global__ __launch_bounds__(256)
void k_prop(const int* __restrict__ obeg, const int* __restrict__ oend,
            const int* __restrict__ srcs, const unsigned short* __restrict__ z,
            unsigned short* __restrict__ zout, const float* __restrict__ invdeg,
            const float* __restrict__ emb, const unsigned short* __restrict__ z1,
            const unsigned short* __restrict__ z2, const float* __restrict__ sdeg,
            float* __restrict__ out, int n) {
  int lane = threadIdx.x & 63;
  int wid = (blockIdx.x * blockDim.x + threadIdx.x) >> 6;   // global wave id
  int g = lane >> 3, l = lane & 7;
  int node = wid * 8 + g;
  if (node >= n) return;
  const uint4* zv = reinterpret_cast<const uint4*>(z);      // row = 8 x uint4
  const int4* sv = reinterpret_cast<const int4*>(srcs);

  const unsigned c_lo = 0x00003F80u;   // B=(1.0bf16, 0)  -> adds lo half
  const unsigned c_hi = 0x3F800000u;   // B=(0, 1.0bf16)  -> adds hi half

  int kq = obeg[node] >> 2;       // even by construction (pad8)
  int endq = oend[node] >> 2;     // endq - kq is even

  float s0 = 0.f, s1 = 0.f, s2 = 0.f, s3 = 0.f;
  float s4 = 0.f, s5 = 0.f, s6 = 0.f, s7 = 0.f;

  int4 sqA = make_int4(0, 0, 0, 0), sqB = sqA;
  if (kq < endq) { sqA = sv[kq]; sqB = sv[kq + 1]; }
  while (kq < endq) {
    uint4 a0 = zv[(size_t)sqA.x * 8 + l];
    uint4 a1 = zv[(size_t)sqA.y * 8 + l];
    uint4 a2 = zv[(size_t)sqA.z * 8 + l];
    uint4 a3 = zv[(size_t)sqA.w * 8 + l];
    uint4 b0 = zv[(size_t)sqB.x * 8 + l];
    uint4 b1 = zv[(size_t)sqB.y * 8 + l];
    uint4 b2 = zv[(size_t)sqB.z * 8 + l];
    uint4 b3 = zv[(size_t)sqB.w * 8 + l];
    kq += 2;
    int nk = (kq < endq) ? kq : (kq - 2);   // harmless re-read at the tail
    sqA = sv[nk];
    sqB = sv[nk + 1];
    ACC2(a0.x, s0, s1); ACC2(a0.y, s2, s3); ACC2(a0.z, s4, s5); ACC2(a0.w, s6, s7);
    ACC2(a1.x, s0, s1); ACC2(a1.y, s2, s3); ACC2(a1.z, s4, s5); ACC2(a1.w, s6, s7);
    ACC2(a2.x, s0, s1); ACC2(a2.y, s2, s3); ACC2(a2.z, s4, s5); ACC2(a2.w, s6, s7);
    ACC2(a3.x, s0, s1); ACC2(a3.y, s2, s3); ACC2(a3.z, s4, s5); ACC2(a3.w, s6, s7);
    ACC2(b0.x, s0, s1); ACC2(b0.y, s2, s3); ACC2(b0.z, s4, s5); ACC2(b0.w, s6, s7);
    ACC2(b1.x, s0, s1); ACC2(b1.y, s2, s3); ACC2(b1.z, s4, s5); ACC2(b1.w, s6, s7);
    ACC2(b2.x, s0, s1); ACC2(b2.y, s2, s3); ACC2(b2.z, s4, s5); ACC2(b2.w, s6, s7);
    ACC2(b3.x, s0, s1); ACC2(b3.y, s2, s3); ACC2(b3.z, s4, s5); ACC2(b3.w, s6, s7);
  }

  float idg = invdeg[node];
  size_t gi = (size_t)node * 8 + l;
  if (!FINAL) {
    uint4 o;
    o.x = cvt_pk_bf16(s0 * idg, s1 * idg);
    o.y = cvt_pk_bf16(s2 * idg, s3 * idg);
    o.z = cvt_pk_bf16(s4 * idg, s5 * idg);
    o.w = cvt_pk_bf16(s6 * idg, s7 * idg);
    reinterpret_cast<uint4*>(zout)[gi] = o;
  } else {
    float sd = sdeg[node];
    float c = sd * idg;
    uint4 a1 = reinterpret_cast<const uint4*>(z1)[gi];
    uint4 a2 = reinterpret_cast<const uint4*>(z2)[gi];
    float4 e0 = reinterpret_cast<const float4*>(emb)[(size_t)node * 16 + 2 * l];
    float4 e1 = reinterpret_cast<const float4*>(emb)[(size_t)node * 16 + 2 * l + 1];
    float4 o0, o1;
    o0.x = 0.25f * (e0.x + sd * (lo2f(a1.x) + lo2f(a2.x)) + c * s0);
    o0.y = 0.25f * (e0.y + sd * (hi2f(a1.x) + hi2f(a2.x)) + c * s1);
    o0.z = 0.25f * (e0.z + sd * (lo2f(a1.y) + lo2f(a2.y)) + c * s2);
    o0.w = 0.25f * (e0.w + sd * (hi2f(a1.y) + hi2f(a2.y)) + c * s3);
    o1.x = 0.25f * (e1.x + sd * (lo2f(a1.z) + lo2f(a2.z)) + c * s4);
    o1.y = 0.25f * (e1.y + sd * (hi2f(a1.z) + hi2f(a2.z)) + c * s5);
    o1.z = 0.25f * (e1.z + sd * (lo2f(a1.w) + lo2f(a2.w)) + c * s6);
    o1.w = 0.25f * (e1.w + sd * (hi2f(a1.w) + hi2f(a2.w)) + c * s7);
    reinterpret_cast<float4*>(out)[(size_t)node * 16 + 2 * l] = o0;
    reinterpret_cast<float4*>(out)[(size_t)node * 16 + 2 * l + 1] = o1;
  }
}

extern "C" void kernel_launch(void* const* d_in, const int* in_sizes, int n_in,
                              void* d_out, int out_size, void* d_ws, size_t ws_size,
                              hipStream_t stream) {
  const int* edge = (const int*)d_in[0];
  const float* emb = (const float*)d_in[1];
  float* out = (float*)d_out;

  const int E = in_sizes[0] / 2;
  const int n = in_sizes[1] / 64;
  const int* row = edge;        // sources j
  const int* col = edge + E;    // targets i
  const int NBKT = (n + BKT_NODES - 1) / BKT_NODES;   // 782

  char* ws = (char*)d_ws;
  size_t off = 0;
  auto alloc = [&](size_t bytes) -> void* {
    void* p = ws + off;
    off += (bytes + 255) & ~(size_t)255;
    return p;
  };
  int*   bcursor = (int*)  alloc((size_t)NBKT * 4);
  int*   tmp     = (int*)  alloc((size_t)NBKT * BKT_CAP * 4);   // ~8.8 MB
  int*   srcs    = (int*)  alloc((size_t)NBKT * BKT_CAP * 4);   // ~8.8 MB
  int*   obeg    = (int*)  alloc((size_t)n * 4);
  int*   oend    = (int*)  alloc((size_t)n * 4);
  float* invdeg  = (float*)alloc((size_t)n * 4);
  float* sdeg    = (float*)alloc((size_t)n * 4);
  unsigned short* z0 = (unsigned short*)alloc((size_t)(n + 1) * 64 * 2);
  unsigned short* z1 = (unsigned short*)alloc((size_t)(n + 1) * 64 * 2);
  unsigned short* z2 = (unsigned short*)alloc((size_t)(n + 1) * 64 * 2);
  (void)ws_size; (void)n_in; (void)out_size;

  const int NBB = (E + EPB - 1) / EPB;    // 153
  k_init<<<(NBKT + 255) / 256, 256, 0, stream>>>(bcursor, NBKT,
      (unsigned*)z0, (unsigned*)z1, (unsigned*)z2, n);
  k_bin<<<NBB, 256, 0, stream>>>(row, col, bcursor, tmp, E, NBKT);
  k_sort<<<NBKT, 256, 0, stream>>>(bcursor, tmp, srcs, obeg, oend,
                                   invdeg, sdeg, emb, z0, n);

  // 8 nodes per wave, 4 waves per block = 32 nodes/block
  const int pg = (n + 31) / 32;
  k_prop<false><<<pg, 256, 0, stream>>>(obeg, oend, srcs, z0, z1, invdeg,
                                        nullptr, nullptr, nullptr, nullptr, nullptr, n);
  k_prop<false><<<pg, 256, 0, stream>>>(obeg, oend, srcs, z1, z2, invdeg,
                                        nullptr, nullptr, nullptr, nullptr, nullptr, n);
  k_prop<true ><<<pg, 256, 0, stream>>>(obeg, oend, srcs, z2, nullptr, invdeg,
                                        emb, z1, z2, sdeg, out, n);
}

// Round 14
// 120.576 us; speedup vs baseline: 1.5978x; 1.0462x over previous
//
#include <hip/hip_runtime.h>

// LightGCN, z-form: z = dis(.)x  =>  z_k[c] = invdeg_c * sum_{r->c} z_{k-1}[r]
//   out = 0.25*(emb + sdeg (.) (z1+z2+z3)),  sdeg = sqrt(deg), dis = 1/sdeg.
// Build: radix partition by target bucket (128 nodes), per-bucket counting
// sort -> per-node CSR PADDED to multiple of 8 (dummy src = n -> zero row).
// Prop: 8-lane group per node (8 nodes/wave), lane = uint4 = 8 bf16 dims,
// guard-free 8-edge (2-quad) unroll; bf16 accumulate via v_dot2_f32_bf16.
// NOTES: coop fusion (R8/R9) 6x slower. Per-node src sort (R11) regressed.
// Prop loop fabric-bound: FETCH == 8 XCD x z_size compulsory floor (R9/R10/
// R12 all null). k_bin R13: EPB revert fixed WRITE but not dur (40us) ->
// this round: col kept in regs (single read), int4 loads, 4-wide unroll.

#define BKT_SHIFT 7
#define BKT_NODES 128
#define BKT_CAP   2816      // mean 1600 edges + pad8 + slack
#define EPB       4096      // edges per k_bin block (306 blocks, 16/thread)

__device__ __forceinline__ float lo2f(unsigned u) { return __uint_as_float(u << 16); }
__device__ __forceinline__ float hi2f(unsigned u) { return __uint_as_float(u & 0xFFFF0000u); }
__device__ __forceinline__ unsigned cvt_pk_bf16(float lo, float hi) {
  unsigned r;
  asm("v_cvt_pk_bf16_f32 %0, %1, %2" : "=v"(r) : "v"(lo), "v"(hi));
  return r;
}

// s_lo += bf16_lo(u); s_hi += bf16_hi(u)  — one v_dot2 each (B=(1,0)/(0,1))
#define ACC2(u, slo, shi)                                                     \
  asm("v_dot2_f32_bf16 %0, %1, %2, %0" : "+v"(slo) : "v"(u), "v"(c_lo));      \
  asm("v_dot2_f32_bf16 %0, %1, %2, %0" : "+v"(shi) : "v"(u), "v"(c_hi));

__device__ __forceinline__ int wave_scan_incl(int v, int lane) {
#pragma unroll
  for (int off = 1; off < 64; off <<= 1) {
    int t = __shfl_up(v, off, 64);
    if (lane >= off) v += t;
  }
  return v;
}

// init bucket cursors + zero the dummy row n of z0/z1/z2
__global__ void k_init(int* __restrict__ bcursor, int nbkt,
                       unsigned* __restrict__ z0, unsigned* __restrict__ z1,
                       unsigned* __restrict__ z2, int n) {
  int i = blockIdx.x * blockDim.x + threadIdx.x;
  if (i < nbkt) bcursor[i] = i * BKT_CAP;
  if (blockIdx.x == 0 && threadIdx.x < 32) {     // row = 64 bf16 = 32 uints
    size_t o = (size_t)n * 32 + threadIdx.x;
    z0[o] = 0u; z1[o] = 0u; z2[o] = 0u;
  }
}

// radix partition by target bucket; col read ONCE into registers (int4),
// 4-wide unrolled LDS-atomic phases, grouped reservation (1 global atomic
// per (block,bin)).
__global__ __launch_bounds__(256)
void k_bin(const int* __restrict__ row, const int* __restrict__ col,
           int* __restrict__ bcursor, int* __restrict__ tmp, int E, int nbkt) {
  __shared__ int h[1024];                 // nbkt <= 1024
  int e0 = blockIdx.x * EPB;
  int rem = min(EPB, E - e0);             // edges in this block
  for (int i = threadIdx.x; i < nbkt; i += 256) h[i] = 0;
  __syncthreads();

  int cv[16];
  const int t4 = threadIdx.x << 2;        // 4 consecutive edges per load
#pragma unroll
  for (int k = 0; k < 4; ++k) {
    int base = t4 + (k << 10);            // + k*1024
    if (base + 3 < rem) {
      int4 c4 = *reinterpret_cast<const int4*>(col + e0 + base);
      cv[4 * k + 0] = c4.x; cv[4 * k + 1] = c4.y;
      cv[4 * k + 2] = c4.z; cv[4 * k + 3] = c4.w;
      atomicAdd(&h[c4.x >> BKT_SHIFT], 1);
      atomicAdd(&h[c4.y >> BKT_SHIFT], 1);
      atomicAdd(&h[c4.z >> BKT_SHIFT], 1);
      atomicAdd(&h[c4.w >> BKT_SHIFT], 1);
    } else {
#pragma unroll
      for (int j = 0; j < 4; ++j) {
        int li = base + j;
        int c = (li < rem) ? col[e0 + li] : -1;
        cv[4 * k + j] = c;
        if (c >= 0) atomicAdd(&h[c >> BKT_SHIFT], 1);
      }
    }
  }
  __syncthreads();
  for (int i = threadIdx.x; i < nbkt; i += 256) {
    int c = h[i];
    h[i] = c ? atomicAdd(&bcursor[i], c) : 0;   // reserve range, h -> base
  }
  __syncthreads();
#pragma unroll
  for (int k = 0; k < 4; ++k) {
    int base = t4 + (k << 10);
    if (base + 3 < rem) {
      int4 r4 = *reinterpret_cast<const int4*>(row + e0 + base);
      int c0 = cv[4 * k + 0], c1 = cv[4 * k + 1];
      int c2 = cv[4 * k + 2], c3 = cv[4 * k + 3];
      int p0 = atomicAdd(&h[c0 >> BKT_SHIFT], 1);
      int p1 = atomicAdd(&h[c1 >> BKT_SHIFT], 1);
      int p2 = atomicAdd(&h[c2 >> BKT_SHIFT], 1);
      int p3 = atomicAdd(&h[c3 >> BKT_SHIFT], 1);
      tmp[p0] = r4.x | ((c0 & (BKT_NODES - 1)) << 20);
      tmp[p1] = r4.y | ((c1 & (BKT_NODES - 1)) << 20);
      tmp[p2] = r4.z | ((c2 & (BKT_NODES - 1)) << 20);
      tmp[p3] = r4.w | ((c3 & (BKT_NODES - 1)) << 20);
    } else {
#pragma unroll
      for (int j = 0; j < 4; ++j) {
        int li = base + j;
        int c = cv[4 * k + j];
        if (c >= 0) {
          int r = row[e0 + li];
          int p = atomicAdd(&h[c >> BKT_SHIFT], 1);
          tmp[p] = r | ((c & (BKT_NODES - 1)) << 20);
        }
      }
    }
  }
}

// per-bucket counting sort -> pad8 per-node CSR; deg stats; z0 = bf16(dis*emb)
__global__ __launch_bounds__(256)
void k_sort(const int* __restrict__ bcursor, const int* __restrict__ tmp,
            int* __restrict__ srcs, int* __restrict__ obeg, int* __restrict__ oend,
            float* __restrict__ invdeg, float* __restrict__ sdeg,
            const float* __restrict__ emb, unsigned short* __restrict__ z0, int n) {
  __shared__ int hist[BKT_NODES];
  __shared__ int excl[BKT_NODES];
  __shared__ int cur[BKT_NODES];
  __shared__ float sdis[BKT_NODES];
  int b = blockIdx.x;
  int base = b * BKT_CAP;
  int cnt = bcursor[b] - base;
  if (threadIdx.x < BKT_NODES) hist[threadIdx.x] = 0;
  __syncthreads();
  for (int q = threadIdx.x; q < cnt; q += 256)
    atomicAdd(&hist[(unsigned)tmp[base + q] >> 20], 1);
  __syncthreads();
  if (threadIdx.x < 64) {     // scan PAD8 lengths; lane l owns bins 2l, 2l+1
    int l = threadIdx.x;
    int h0 = hist[2 * l], h1 = hist[2 * l + 1];
    int p0 = (h0 + 7) & ~7, p1 = (h1 + 7) & ~7;
    int v = p0 + p1;
    int incl = wave_scan_incl(v, l);
    int ex = incl - v;
    excl[2 * l] = ex;      excl[2 * l + 1] = ex + p0;
    cur[2 * l] = ex;       cur[2 * l + 1] = ex + p0;
  }
  __syncthreads();
  int node0 = b << BKT_SHIFT;
  if (threadIdx.x < BKT_NODES) {
    int node = node0 + threadIdx.x;
    if (node < n) {
      int d = hist[threadIdx.x];
      int dpad = (d + 7) & ~7;
      int bg = base + excl[threadIdx.x];
      obeg[node] = bg;
      oend[node] = bg + dpad;                 // padded end for the walk
      float fd = (float)d;
      invdeg[node] = d ? 1.0f / fd : 0.0f;
      sdeg[node] = sqrtf(fd);
      sdis[threadIdx.x] = d ? rsqrtf(fd) : 0.0f;
      for (int p = d; p < dpad; ++p) srcs[bg + p] = n;   // dummy -> zero row
    } else {
      sdis[threadIdx.x] = 0.0f;
    }
  }
  __syncthreads();
  for (int q = threadIdx.x; q < cnt; q += 256) {
    int rec = tmp[base + q];
    int lc = (unsigned)rec >> 20;
    int p = atomicAdd(&cur[lc], 1);
    srcs[base + p] = rec & 0xFFFFF;
  }
  int nloc = min(BKT_NODES, n - node0);
  for (int t = threadIdx.x; t < nloc * 8; t += 256) {
    int rr = t >> 3, q = t & 7;
    float ds = sdis[rr];
    float4 v0 = reinterpret_cast<const float4*>(emb)[(size_t)(node0 + rr) * 16 + 2 * q];
    float4 v1 = reinterpret_cast<const float4*>(emb)[(size_t)(node0 + rr) * 16 + 2 * q + 1];
    uint4 o;
    o.x = cvt_pk_bf16(v0.x * ds, v0.y * ds);
    o.y = cvt_pk_bf16(v0.z * ds, v0.w * ds);
    o.z = cvt_pk_bf16(v1.x * ds, v1.y * ds);
    o.w = cvt_pk_bf16(v1.z * ds, v1.w * ds);
    reinterpret_cast<uint4*>(z0)[(size_t)(node0 + rr) * 8 + q] = o;
  }
}

// 8-lane group per node, 8 nodes per wave; lane l covers dims 8l..8l+7 (uint4).
// Guard-free 2-quad (8-edge) unroll over pad8 CSR; dot2-based accumulate.
template <bool FINAL>
__global__ __launch_bounds__(256)
void k_prop(const int* __restrict__ obeg, const int* __restrict__ oend,
            const int* __restrict__ srcs, const unsigned short* __restrict__ z,
            unsigned short* __restrict__ zout, const float* __restrict__ invdeg,
            const float* __restrict__ emb, const unsigned short* __restrict__ z1,
            const unsigned short* __restrict__ z2, const float* __restrict__ sdeg,
            float* __restrict__ out, int n) {
  int lane = threadIdx.x & 63;
  int wid = (blockIdx.x * blockDim.x + threadIdx.x) >> 6;   // global wave id
  int g = lane >> 3, l = lane & 7;
  int node = wid * 8 + g;
  if (node >= n) return;
  const uint4* zv = reinterpret_cast<const uint4*>(z);      // row = 8 x uint4
  const int4* sv = reinterpret_cast<const int4*>(srcs);

  const unsigned c_lo = 0x00003F80u;   // B=(1.0bf16, 0)  -> adds lo half
  const unsigned c_hi = 0x3F800000u;   // B=(0, 1.0bf16)  -> adds hi half

  int kq = obeg[node] >> 2;       // even by construction (pad8)
  int endq = oend[node] >> 2;     // endq - kq is even

  float s0 = 0.f, s1 = 0.f, s2 = 0.f, s3 = 0.f;
  float s4 = 0.f, s5 = 0.f, s6 = 0.f, s7 = 0.f;

  int4 sqA = make_int4(0, 0, 0, 0), sqB = sqA;
  if (kq < endq) { sqA = sv[kq]; sqB = sv[kq + 1]; }
  while (kq < endq) {
    uint4 a0 = zv[(size_t)sqA.x * 8 + l];
    uint4 a1 = zv[(size_t)sqA.y * 8 + l];
    uint4 a2 = zv[(size_t)sqA.z * 8 + l];
    uint4 a3 = zv[(size_t)sqA.w * 8 + l];
    uint4 b0 = zv[(size_t)sqB.x * 8 + l];
    uint4 b1 = zv[(size_t)sqB.y * 8 + l];
    uint4 b2 = zv[(size_t)sqB.z * 8 + l];
    uint4 b3 = zv[(size_t)sqB.w * 8 + l];
    kq += 2;
    int nk = (kq < endq) ? kq : (kq - 2);   // harmless re-read at the tail
    sqA = sv[nk];
    sqB = sv[nk + 1];
    ACC2(a0.x, s0, s1); ACC2(a0.y, s2, s3); ACC2(a0.z, s4, s5); ACC2(a0.w, s6, s7);
    ACC2(a1.x, s0, s1); ACC2(a1.y, s2, s3); ACC2(a1.z, s4, s5); ACC2(a1.w, s6, s7);
    ACC2(a2.x, s0, s1); ACC2(a2.y, s2, s3); ACC2(a2.z, s4, s5); ACC2(a2.w, s6, s7);
    ACC2(a3.x, s0, s1); ACC2(a3.y, s2, s3); ACC2(a3.z, s4, s5); ACC2(a3.w, s6, s7);
    ACC2(b0.x, s0, s1); ACC2(b0.y, s2, s3); ACC2(b0.z, s4, s5); ACC2(b0.w, s6, s7);
    ACC2(b1.x, s0, s1); ACC2(b1.y, s2, s3); ACC2(b1.z, s4, s5); ACC2(b1.w, s6, s7);
    ACC2(b2.x, s0, s1); ACC2(b2.y, s2, s3); ACC2(b2.z, s4, s5); ACC2(b2.w, s6, s7);
    ACC2(b3.x, s0, s1); ACC2(b3.y, s2, s3); ACC2(b3.z, s4, s5); ACC2(b3.w, s6, s7);
  }

  float idg = invdeg[node];
  size_t gi = (size_t)node * 8 + l;
  if (!FINAL) {
    uint4 o;
    o.x = cvt_pk_bf16(s0 * idg, s1 * idg);
    o.y = cvt_pk_bf16(s2 * idg, s3 * idg);
    o.z = cvt_pk_bf16(s4 * idg, s5 * idg);
    o.w = cvt_pk_bf16(s6 * idg, s7 * idg);
    reinterpret_cast<uint4*>(zout)[gi] = o;
  } else {
    float sd = sdeg[node];
    float c = sd * idg;
    uint4 a1 = reinterpret_cast<const uint4*>(z1)[gi];
    uint4 a2 = reinterpret_cast<const uint4*>(z2)[gi];
    float4 e0 = reinterpret_cast<const float4*>(emb)[(size_t)node * 16 + 2 * l];
    float4 e1 = reinterpret_cast<const float4*>(emb)[(size_t)node * 16 + 2 * l + 1];
    float4 o0, o1;
    o0.x = 0.25f * (e0.x + sd * (lo2f(a1.x) + lo2f(a2.x)) + c * s0);
    o0.y = 0.25f * (e0.y + sd * (hi2f(a1.x) + hi2f(a2.x)) + c * s1);
    o0.z = 0.25f * (e0.z + sd * (lo2f(a1.y) + lo2f(a2.y)) + c * s2);
    o0.w = 0.25f * (e0.w + sd * (hi2f(a1.y) + hi2f(a2.y)) + c * s3);
    o1.x = 0.25f * (e1.x + sd * (lo2f(a1.z) + lo2f(a2.z)) + c * s4);
    o1.y = 0.25f * (e1.y + sd * (hi2f(a1.z) + hi2f(a2.z)) + c * s5);
    o1.z = 0.25f * (e1.z + sd * (lo2f(a1.w) + lo2f(a2.w)) + c * s6);
    o1.w = 0.25f * (e1.w + sd * (hi2f(a1.w) + hi2f(a2.w)) + c * s7);
    reinterpret_cast<float4*>(out)[(size_t)node * 16 + 2 * l] = o0;
    reinterpret_cast<float4*>(out)[(size_t)node * 16 + 2 * l + 1] = o1;
  }
}

extern "C" void kernel_launch(void* const* d_in, const int* in_sizes, int n_in,
                              void* d_out, int out_size, void* d_ws, size_t ws_size,
                              hipStream_t stream) {
  const int* edge = (const int*)d_in[0];
  const float* emb = (const float*)d_in[1];
  float* out = (float*)d_out;

  const int E = in_sizes[0] / 2;
  const int n = in_sizes[1] / 64;
  const int* row = edge;        // sources j
  const int* col = edge + E;    // targets i
  const int NBKT = (n + BKT_NODES - 1) / BKT_NODES;   // 782

  char* ws = (char*)d_ws;
  size_t off = 0;
  auto alloc = [&](size_t bytes) -> void* {
    void* p = ws + off;
    off += (bytes + 255) & ~(size_t)255;
    return p;
  };
  int*   bcursor = (int*)  alloc((size_t)NBKT * 4);
  int*   tmp     = (int*)  alloc((size_t)NBKT * BKT_CAP * 4);   // ~8.8 MB
  int*   srcs    = (int*)  alloc((size_t)NBKT * BKT_CAP * 4);   // ~8.8 MB
  int*   obeg    = (int*)  alloc((size_t)n * 4);
  int*   oend    = (int*)  alloc((size_t)n * 4);
  float* invdeg  = (float*)alloc((size_t)n * 4);
  float* sdeg    = (float*)alloc((size_t)n * 4);
  unsigned short* z0 = (unsigned short*)alloc((size_t)(n + 1) * 64 * 2);
  unsigned short* z1 = (unsigned short*)alloc((size_t)(n + 1) * 64 * 2);
  unsigned short* z2 = (unsigned short*)alloc((size_t)(n + 1) * 64 * 2);
  (void)ws_size; (void)n_in; (void)out_size;

  const int NBB = (E + EPB - 1) / EPB;    // 306
  k_init<<<(NBKT + 255) / 256, 256, 0, stream>>>(bcursor, NBKT,
      (unsigned*)z0, (unsigned*)z1, (unsigned*)z2, n);
  k_bin<<<NBB, 256, 0, stream>>>(row, col, bcursor, tmp, E, NBKT);
  k_sort<<<NBKT, 256, 0, stream>>>(bcursor, tmp, srcs, obeg, oend,
                                   invdeg, sdeg, emb, z0, n);

  // 8 nodes per wave, 4 waves per block = 32 nodes/block
  const int pg = (n + 31) / 32;
  k_prop<false><<<pg, 256, 0, stream>>>(obeg, oend, srcs, z0, z1, invdeg,
                                        nullptr, nullptr, nullptr, nullptr, nullptr, n);
  k_prop<false><<<pg, 256, 0, stream>>>(obeg, oend, srcs, z1, z2, invdeg,
                                        nullptr, nullptr, nullptr, nullptr, nullptr, n);
  k_prop<true ><<<pg, 256, 0, stream>>>(obeg, oend, srcs, z2, nullptr, invdeg,
                                        emb, z1, z2, sdeg, out, n);
}